// Round 10
// baseline (287.194 us; speedup 1.0000x reference)
//
#include <hip/hip_runtime.h>

typedef float  f32x4  __attribute__((ext_vector_type(4)));
typedef __bf16 bf16x8 __attribute__((ext_vector_type(8)));
typedef unsigned short ushort_t;

#define N_PTS 4096
#define R_ROIS 128
#define M_GP  27648
#define LDS_FENCE() asm volatile("s_waitcnt lgkmcnt(0)" ::: "memory")

// ---------------- workspace layout (bytes), total 13,763,072 ----------------
static constexpr size_t OFF_GP     = 0;          // 331,776
// A-fragment arrays (pool output, s1 input): [432][128][32] u16 each
static constexpr size_t OFF_PH     = 331776;     // 3,538,944
static constexpr size_t OFF_PL     = 3870720;    // 3,538,944 (end 7,409,664)
// h1s/h2s overlay the A-frag region (dead after s1 GEMM):
static constexpr size_t OFF_H1H    = 331776;     // 3*128*1024*2 = 786,432
static constexpr size_t OFF_H1L    = 1118208;    // 786,432
static constexpr size_t OFF_H2S    = 1904640;    // 786,432 (end 2,691,072)
static constexpr size_t OFF_PART   = 7409664;    // 8*128*1024*4 = 4,194,304 (end 11,603,968)
//   pool-phase overlays inside PART (dead before s1 writes it):
static constexpr size_t OFF_CAND   = OFF_PART;   // 2,097,152
static constexpr size_t OFF_F      = 9506816;    // 4096*64*4 = 1,048,576
static constexpr size_t OFF_NCAND  = 11603968;   // 512
static constexpr size_t OFF_W1TH   = 11604480;   // 10752*2
static constexpr size_t OFF_W1TL   = 11625984;   // 10752*2
static constexpr size_t OFF_W2TH   = 11647488;   // 4608*2
static constexpr size_t OFF_W2TL   = 11656704;   // 4608*2 (end 11,665,920)
// fhi/flo live until f_gemm; t1/sfc (FC phase) overlay them:
static constexpr size_t OFF_FHI    = 11665920;   // 1,048,576
static constexpr size_t OFF_FLO    = 12714496;   // 1,048,576 (end 13,763,072)
static constexpr size_t OFF_T1H    = 11665920;   // 262,144
static constexpr size_t OFF_T1L    = 11928064;   // 262,144
static constexpr size_t OFF_SFCH   = 12190208;   // 131,072
static constexpr size_t OFF_SFCL   = 12321280;   // 131,072 (end 12,452,352)

static __device__ inline ushort_t f2bf(float f) {
    unsigned int u = __float_as_uint(f);
    unsigned int r = u + 0x7FFFu + ((u >> 16) & 1u);
    return (ushort_t)(r >> 16);
}
static __device__ inline float bf2f(ushort_t h) {
    return __uint_as_float(((unsigned int)h) << 16);
}

// ---------------- merged prep: grid points | weight prep | feats prep | roi cand
__global__ __launch_bounds__(256) void prep_all_k(
    const float* __restrict__ rois, const float* __restrict__ xyz,
    const float* __restrict__ feats, const float* __restrict__ w1,
    const float* __restrict__ w2, float* __restrict__ gp,
    ushort_t* __restrict__ fhi, ushort_t* __restrict__ flo,
    ushort_t* __restrict__ w1th, ushort_t* __restrict__ w1tl,
    ushort_t* __restrict__ w2th, ushort_t* __restrict__ w2tl,
    int* __restrict__ cand, int* __restrict__ ncand) {
    int b = blockIdx.x, tid = threadIdx.x;
    if (b < 108) {                       // ---- grid points
        int m = b * 256 + tid;
        int r = m / 216, t = m % 216;
        int gi = t / 36, gj = (t / 6) % 6, gk = t % 6;
        const float* roi = rois + r * 7;
        float sx = roi[3], sy = roi[4], sz = roi[5];
        float lx = ((float)gi + 0.5f) / 6.0f * sx - sx * 0.5f;
        float ly = ((float)gj + 0.5f) / 6.0f * sy - sy * 0.5f;
        float lz = ((float)gk + 0.5f) / 6.0f * sz - sz * 0.5f;
        float c = cosf(roi[6]), s = sinf(roi[6]);
        gp[m * 3 + 0] = lx * c - ly * s + roi[0];
        gp[m * 3 + 1] = lx * s + ly * c + roi[1];
        gp[m * 3 + 2] = lz + roi[2];
    } else if (b < 150) {                // ---- weight prep (permuted transpose + hi/lo)
        int t = (b - 108) * 256 + tid;   // t < 10752
        {
            int col = t / 168, p = t % 168;
            float v = (p < 128) ? w1[(3 + p) * 64 + col]
                    : (p < 131) ? w1[(p - 128) * 64 + col] : 0.f;
            ushort_t hi = f2bf(v);
            w1th[t] = hi;
            w1tl[t] = f2bf(v - bf2f(hi));
        }
        if (t < 4608) {
            int col = t / 72, k = t % 72;
            float v = (k < 64) ? w2[k * 64 + col] : 0.f;
            ushort_t hi = f2bf(v);
            w2th[t] = hi;
            w2tl[t] = f2bf(v - bf2f(hi));
        }
    } else if (b < 2198) {               // ---- feats -> hi/lo bf16
        int i = (b - 150) * 256 + tid;   // i < 524288
        float v = feats[i];
        __bf16 h = (__bf16)v;
        fhi[i] = __builtin_bit_cast(ushort_t, h);
        flo[i] = __builtin_bit_cast(ushort_t, (__bf16)(v - (float)h));
    } else {                             // ---- per-RoI candidate lists (4 waves/block)
        int r = (b - 2198) * 4 + (tid >> 6);
        int lane = tid & 63;
        const float* roi = rois + r * 7;
        float cx = roi[0], cy = roi[1], cz = roi[2];
        float sx = roi[3], sy = roi[4], sz = roi[5];
        float Rc = 0.8f + 0.4166667f * sqrtf(sx * sx + sy * sy + sz * sz) + 0.01f;
        float Rc2 = Rc * Rc;
        int* cl = cand + (size_t)r * N_PTS;
        int cnt = 0;
        for (int base = 0; base < N_PTS; base += 64) {
            int i = base + lane;
            float dx = xyz[i * 3 + 0] - cx;
            float dy = xyz[i * 3 + 1] - cy;
            float dz = xyz[i * 3 + 2] - cz;
            bool in = dx * dx + dy * dy + dz * dz < Rc2;
            unsigned long long ball = __ballot(in);
            int before = __popcll(ball & ((1ull << lane) - 1ull));
            if (in) cl[cnt + before] = i;
            cnt += __popcll(ball);
        }
        if (lane == 0) ncand[r] = cnt;
    }
}

// ---------------- F = feats @ W1f (split-bf16 MFMA), 4096x64 f32 ----------
__global__ __launch_bounds__(256) void f_gemm_k(
    const ushort_t* __restrict__ fhi, const ushort_t* __restrict__ flo,
    const ushort_t* __restrict__ w1th, const ushort_t* __restrict__ w1tl,
    float* __restrict__ F) {
    int tid = threadIdx.x;
    int w = tid >> 6, lane = tid & 63;
    int row = lane & 15, grp = lane >> 4;
    int m0 = blockIdx.x * 64 + w * 16;

    f32x4 acc[4];
#pragma unroll
    for (int nt = 0; nt < 4; nt++) acc[nt] = {0.f, 0.f, 0.f, 0.f};

#pragma unroll
    for (int ks = 0; ks < 4; ks++) {
        size_t ao = (size_t)(m0 + row) * 128 + ks * 32 + grp * 8;
        bf16x8 ah = *(const bf16x8*)&fhi[ao];
        bf16x8 al = *(const bf16x8*)&flo[ao];
#pragma unroll
        for (int nt = 0; nt < 4; nt++) {
            int bo = (nt * 16 + row) * 168 + ks * 32 + grp * 8;
            bf16x8 bh = *(const bf16x8*)&w1th[bo];
            bf16x8 bl = *(const bf16x8*)&w1tl[bo];
            acc[nt] = __builtin_amdgcn_mfma_f32_16x16x32_bf16(ah, bh, acc[nt], 0, 0, 0);
            acc[nt] = __builtin_amdgcn_mfma_f32_16x16x32_bf16(al, bh, acc[nt], 0, 0, 0);
            acc[nt] = __builtin_amdgcn_mfma_f32_16x16x32_bf16(ah, bl, acc[nt], 0, 0, 0);
        }
    }
#pragma unroll
    for (int nt = 0; nt < 4; nt++)
#pragma unroll
        for (int reg = 0; reg < 4; reg++)
            F[(size_t)(m0 + grp * 4 + reg) * 64 + nt * 16 + row] = acc[nt][reg];
}

// ---------------- pool v4: 4 waves/block, 4 gps/wave (16 gps/block) --------
// Per-wave logic identical to v3; waves are fully independent (private
// s_idx rows, no cross-wave barriers). 256-thread blocks lift the per-CU
// workgroup-slot occupancy cap that throttled the 1-wave version.
__global__ __launch_bounds__(256) void grid_pool_v4_k(
    const float* __restrict__ xyz, const float* __restrict__ F,
    const float* __restrict__ gp, const int* __restrict__ cand,
    const int* __restrict__ ncand, const float* __restrict__ w_m1,
    const ushort_t* __restrict__ w2th, const ushort_t* __restrict__ w2tl,
    ushort_t* __restrict__ Afh, ushort_t* __restrict__ Afl) {
    __shared__ int s_idx[4][4][16];
    int tid = threadIdx.x;
    int w = tid >> 6, lane = tid & 63;
    const float R2 = (float)(0.8 * 0.8);
    int row = lane & 15, grp = lane >> 4;
    int m0 = blockIdx.x * 16 + w * 4;

    bool empty[4];
    float gxv[4], gyv[4], gzv[4];

#pragma unroll
    for (int g = 0; g < 4; g++) {
        int m = m0 + g;
        int r = m / 216;
        float gx = gp[m * 3 + 0], gy = gp[m * 3 + 1], gz = gp[m * 3 + 2];
        gxv[g] = gx; gyv[g] = gy; gzv[g] = gz;
        int nc = ncand[r];
        const int* cl = cand + (size_t)r * N_PTS;
        int count = 0;
        for (int base = 0; base < nc; base += 64) {
            int t = base + lane;
            bool in = false;
            int i = 0;
            if (t < nc) {
                i = cl[t];
                float dx = xyz[i * 3 + 0] - gx;
                float dy = xyz[i * 3 + 1] - gy;
                float dz = xyz[i * 3 + 2] - gz;
                in = dx * dx + dy * dy + dz * dz < R2;
            }
            unsigned long long ball = __ballot(in);
            int before = __popcll(ball & ((1ull << lane) - 1ull));
            int pos = count + before;
            if (in && pos < 16) s_idx[w][g][pos] = i;
            count += __popcll(ball);
            if (count >= 16) break;
        }
        int c = min(count, 16);
        empty[g] = (c == 0);
        if (lane == 0) {
            if (c == 0) {
                for (int p = 0; p < 16; p++) s_idx[w][g][p] = 0;
            } else {
                LDS_FENCE();
                int f = s_idx[w][g][0];
                for (int p = c; p < 16; p++) s_idx[w][g][p] = f;
            }
        }
    }
    LDS_FENCE();

    int pi[4];
    float rx[4], ry[4], rz[4];
#pragma unroll
    for (int g = 0; g < 4; g++) {
        pi[g] = s_idx[w][g][row];
        rx[g] = xyz[pi[g] * 3 + 0] - gxv[g];
        ry[g] = xyz[pi[g] * 3 + 1] - gyv[g];
        rz[g] = xyz[pi[g] * 3 + 2] - gzv[g];
    }

    f32x4 p[4][4];
#pragma unroll
    for (int g = 0; g < 4; g++)
#pragma unroll
        for (int nt = 0; nt < 4; nt++) p[g][nt] = {0.f, 0.f, 0.f, 0.f};

#pragma unroll
    for (int ks = 0; ks < 2; ks++) {
        // W1r slice for this lane's 8 channels (rows 0..2 of w_m1, exact fp32)
        float w1r0[8], w1r1[8], w1r2[8];
        {
            const float* wp = w_m1 + ks * 32 + grp * 8;
            *(float4*)&w1r0[0] = *(const float4*)(wp);
            *(float4*)&w1r0[4] = *(const float4*)(wp + 4);
            *(float4*)&w1r1[0] = *(const float4*)(wp + 64);
            *(float4*)&w1r1[4] = *(const float4*)(wp + 68);
            *(float4*)&w1r2[0] = *(const float4*)(wp + 128);
            *(float4*)&w1r2[4] = *(const float4*)(wp + 132);
        }
        bf16x8 zah[4], zal[4];
#pragma unroll
        for (int g = 0; g < 4; g++) {
            const float* Fr = F + (size_t)pi[g] * 64 + ks * 32 + grp * 8;
            float fv[8];
            *(float4*)&fv[0] = *(const float4*)Fr;
            *(float4*)&fv[4] = *(const float4*)(Fr + 4);
            bf16x8 hh, ll;
#pragma unroll
            for (int j = 0; j < 8; j++) {
                float zv = fv[j] + rx[g] * w1r0[j] + ry[g] * w1r1[j] + rz[g] * w1r2[j];
                float v = fmaxf(zv, 0.f);
                __bf16 h = (__bf16)v;
                hh[j] = h;
                ll[j] = (__bf16)(v - (float)h);
            }
            zah[g] = hh; zal[g] = ll;
        }
#pragma unroll
        for (int nt = 0; nt < 4; nt++) {
            int bo = (nt * 16 + row) * 72 + ks * 32 + grp * 8;
            bf16x8 bh = *(const bf16x8*)&w2th[bo];
            bf16x8 bl = *(const bf16x8*)&w2tl[bo];
#pragma unroll
            for (int g = 0; g < 4; g++) {
                p[g][nt] = __builtin_amdgcn_mfma_f32_16x16x32_bf16(zah[g], bh, p[g][nt], 0, 0, 0);
                p[g][nt] = __builtin_amdgcn_mfma_f32_16x16x32_bf16(zal[g], bh, p[g][nt], 0, 0, 0);
                p[g][nt] = __builtin_amdgcn_mfma_f32_16x16x32_bf16(zah[g], bl, p[g][nt], 0, 0, 0);
            }
        }
    }

#pragma unroll
    for (int g = 0; g < 4; g++) {
        int m = m0 + g;
        int r = m / 216, t = m % 216;
#pragma unroll
        for (int nt = 0; nt < 4; nt++) {
            float mv = fmaxf(fmaxf(fmaxf(p[g][nt][0], p[g][nt][1]),
                                   fmaxf(p[g][nt][2], p[g][nt][3])), 0.f);
            mv = fmaxf(mv, __shfl_xor(mv, 16));
            mv = fmaxf(mv, __shfl_xor(mv, 32));
            if (grp == 0) {
                float v = empty[g] ? 0.f : mv;
                __bf16 h = (__bf16)v;
                int kt = t * 2 + (nt >> 1);
                size_t o = ((size_t)kt * 128 + r) * 32 + (nt & 1) * 16 + row;
                Afh[o] = __builtin_bit_cast(ushort_t, h);
                Afl[o] = __builtin_bit_cast(ushort_t, (__bf16)(v - (float)h));
            }
        }
    }
}

// ---------------- s1 v2: streaming split-bf16 MFMA, A-frags direct ---------
// BM=64, BN=32, S=8. grid (32, 2, 8) = 512 blocks, 256 threads.
__global__ __launch_bounds__(256) void s1v2_k(
    const ushort_t* __restrict__ Afh, const ushort_t* __restrict__ Afl,
    const float* __restrict__ B, float* __restrict__ P) {
    __shared__ __attribute__((aligned(16))) ushort_t Bs_h[32][40];
    __shared__ __attribute__((aligned(16))) ushort_t Bs_l[32][40];
    const int N = 1024, STEPS = 54;
    int tid = threadIdx.x;
    int w = tid >> 6, lane = tid & 63;
    int row = lane & 15, grp = lane >> 4;
    int n0 = blockIdx.x * 32, m0 = blockIdx.y * 64;
    int s = blockIdx.z;
    int kt0 = s * STEPS;
    int krow = tid >> 3, nn = (tid & 7) * 4;

    f32x4 acc[2];
    acc[0] = {0.f, 0.f, 0.f, 0.f};
    acc[1] = {0.f, 0.f, 0.f, 0.f};

    int arow = m0 + w * 16 + row;
    size_t aoff = ((size_t)kt0 * 128 + arow) * 32 + grp * 8;
    const float* bp = B + (size_t)(kt0 * 32 + krow) * N + n0 + nn;

    float4 vb = *(const float4*)bp;
    bf16x8 ah = *(const bf16x8*)&Afh[aoff];
    bf16x8 al = *(const bf16x8*)&Afl[aoff];

    for (int kts = 0; kts < STEPS; ++kts) {
        {   // stage current B tile into LDS (transpose + hi/lo convert)
            float vv[4] = {vb.x, vb.y, vb.z, vb.w};
#pragma unroll
            for (int j = 0; j < 4; j++) {
                __bf16 h = (__bf16)vv[j];
                Bs_h[nn + j][krow] = __builtin_bit_cast(ushort_t, h);
                Bs_l[nn + j][krow] = __builtin_bit_cast(ushort_t, (__bf16)(vv[j] - (float)h));
            }
        }
        __syncthreads();
        float4 vb_n;
        bf16x8 ah_n, al_n;
        if (kts + 1 < STEPS) {            // issue next-tile loads early
            bp += 32 * N;
            vb_n = *(const float4*)bp;
            size_t an = aoff + (size_t)(kts + 1) * 4096;
            ah_n = *(const bf16x8*)&Afh[an];
            al_n = *(const bf16x8*)&Afl[an];
        }
#pragma unroll
        for (int ni = 0; ni < 2; ni++) {
            bf16x8 bh = *(const bf16x8*)&Bs_h[ni * 16 + row][grp * 8];
            bf16x8 bl = *(const bf16x8*)&Bs_l[ni * 16 + row][grp * 8];
            acc[ni] = __builtin_amdgcn_mfma_f32_16x16x32_bf16(ah, bh, acc[ni], 0, 0, 0);
            acc[ni] = __builtin_amdgcn_mfma_f32_16x16x32_bf16(al, bh, acc[ni], 0, 0, 0);
            acc[ni] = __builtin_amdgcn_mfma_f32_16x16x32_bf16(ah, bl, acc[ni], 0, 0, 0);
        }
        __syncthreads();
        if (kts + 1 < STEPS) { vb = vb_n; ah = ah_n; al = al_n; }
    }
    size_t pb = (size_t)s * 128 * N;
#pragma unroll
    for (int ni = 0; ni < 2; ni++)
#pragma unroll
        for (int reg = 0; reg < 4; reg++) {
            int mrow = m0 + w * 16 + grp * 4 + reg;
            P[pb + (size_t)mrow * N + n0 + ni * 16 + row] = acc[ni][reg];
        }
}

// ======== split-bf16 MFMA GEMM: A pre-split u16 hi/lo, B f32 ========
// BM=128, BN=64, BK=32, 256 threads. (used by s2 / heads — K <= 1024)
__device__ inline void gemm_body(const ushort_t* __restrict__ Ah,
                                 const ushort_t* __restrict__ Al,
                                 const float* __restrict__ B,
                                 f32x4 (&acc)[2][4],
                                 int N, int Kt, int k0, int klen, int n0) {
    __shared__ __attribute__((aligned(16))) ushort_t As_h[128][40];
    __shared__ __attribute__((aligned(16))) ushort_t As_l[128][40];
    __shared__ __attribute__((aligned(16))) ushort_t Bs_h[64][40];
    __shared__ __attribute__((aligned(16))) ushort_t Bs_l[64][40];
    int tid = threadIdx.x;
    int w = tid >> 6, lane = tid & 63;
    int row = lane & 15, grp = lane >> 4;

    for (int kt = 0; kt < klen; kt += 32) {
        {   // A copy: 128 rows x 32 u16 per array; 2 threads/row, 2 uint4 each
            int arow = tid >> 1, koff = (tid & 1) * 16;
            size_t so = (size_t)arow * Kt + k0 + kt + koff;
            *(uint4*)&As_h[arow][koff]     = *(const uint4*)(Ah + so);
            *(uint4*)&As_h[arow][koff + 8] = *(const uint4*)(Ah + so + 8);
            *(uint4*)&As_l[arow][koff]     = *(const uint4*)(Al + so);
            *(uint4*)&As_l[arow][koff + 8] = *(const uint4*)(Al + so + 8);
        }
        {   // B stage + convert, transposed: Bs[n][k]
            int kr = tid >> 4;
            int nn = (tid & 15) * 4;
#pragma unroll
            for (int i = 0; i < 2; i++) {
                int krow = kr + i * 16;
                float4 v = *(const float4*)(B + (size_t)(k0 + kt + krow) * N + n0 + nn);
                float vv[4] = {v.x, v.y, v.z, v.w};
#pragma unroll
                for (int j = 0; j < 4; j++) {
                    __bf16 h = (__bf16)vv[j];
                    Bs_h[nn + j][krow] = __builtin_bit_cast(ushort_t, h);
                    Bs_l[nn + j][krow] = __builtin_bit_cast(ushort_t, (__bf16)(vv[j] - (float)h));
                }
            }
        }
        __syncthreads();
#pragma unroll
        for (int mi = 0; mi < 2; mi++) {
            int arow = (w * 2 + mi) * 16 + row;
            bf16x8 ah = *(const bf16x8*)&As_h[arow][grp * 8];
            bf16x8 al = *(const bf16x8*)&As_l[arow][grp * 8];
#pragma unroll
            for (int ni = 0; ni < 4; ni++) {
                bf16x8 bh = *(const bf16x8*)&Bs_h[ni * 16 + row][grp * 8];
                bf16x8 bl = *(const bf16x8*)&Bs_l[ni * 16 + row][grp * 8];
                acc[mi][ni] = __builtin_amdgcn_mfma_f32_16x16x32_bf16(ah, bh, acc[mi][ni], 0, 0, 0);
                acc[mi][ni] = __builtin_amdgcn_mfma_f32_16x16x32_bf16(al, bh, acc[mi][ni], 0, 0, 0);
                acc[mi][ni] = __builtin_amdgcn_mfma_f32_16x16x32_bf16(ah, bl, acc[mi][ni], 0, 0, 0);
            }
        }
        __syncthreads();
    }
}

// fused full-K GEMM + relu; out bf16 hi/lo or f32. grid (N/64, 1, heads)
__global__ __launch_bounds__(256) void fused_gemm_k(
    const ushort_t* __restrict__ A_h, const ushort_t* __restrict__ A_l,
    size_t a_stride,
    const float* __restrict__ B0, const float* __restrict__ B1,
    const float* __restrict__ B2,
    ushort_t* __restrict__ C_h, ushort_t* __restrict__ C_l,
    float* __restrict__ C_f, int out_f32, int N, int Kt) {
    int tid = threadIdx.x;
    int w = tid >> 6, lane = tid & 63;
    int row = lane & 15, grp = lane >> 4;
    int head = blockIdx.z, n0 = blockIdx.x * 64;
    const float* B = (head == 0) ? B0 : (head == 1) ? B1 : B2;
    const ushort_t* Ah = A_h + (size_t)head * a_stride;
    const ushort_t* Al = A_l + (size_t)head * a_stride;
    f32x4 acc[2][4];
#pragma unroll
    for (int mi = 0; mi < 2; mi++)
#pragma unroll
        for (int ni = 0; ni < 4; ni++) acc[mi][ni] = {0.f, 0.f, 0.f, 0.f};
    gemm_body(Ah, Al, B, acc, N, Kt, 0, Kt, n0);
    size_t ob = (size_t)head * 128 * N;
#pragma unroll
    for (int mi = 0; mi < 2; mi++)
#pragma unroll
        for (int ni = 0; ni < 4; ni++)
#pragma unroll
            for (int reg = 0; reg < 4; reg++) {
                int mrow = (w * 2 + mi) * 16 + grp * 4 + reg;
                size_t o = ob + (size_t)mrow * N + n0 + ni * 16 + row;
                float v = fmaxf(acc[mi][ni][reg], 0.f);
                if (out_f32) {
                    C_f[o] = v;
                } else {
                    __bf16 h = (__bf16)v;
                    C_h[o] = __builtin_bit_cast(ushort_t, h);
                    C_l[o] = __builtin_bit_cast(ushort_t, (__bf16)(v - (float)h));
                }
            }
}

// reduce partials + relu -> hi/lo bf16
__global__ __launch_bounds__(256) void reduce_bf_k(const float* __restrict__ P,
                                                   ushort_t* __restrict__ C_h,
                                                   ushort_t* __restrict__ C_l,
                                                   int MN, int S) {
    int i = blockIdx.x * 256 + threadIdx.x;
    if (i >= MN) return;
    float v = 0.f;
    for (int s = 0; s < S; s++) v += P[(size_t)s * MN + i];
    v = fmaxf(v, 0.f);
    __bf16 h = (__bf16)v;
    C_h[i] = __builtin_bit_cast(ushort_t, h);
    C_l[i] = __builtin_bit_cast(ushort_t, (__bf16)(v - (float)h));
}

// ---------------- final head projections (merged) ----------------
__global__ __launch_bounds__(256) void head_out3_k(
    const float* __restrict__ h2s, const float* __restrict__ w_c3,
    const float* __restrict__ w_i3, const float* __restrict__ w_r3,
    const float* __restrict__ b_c3, const float* __restrict__ b_i3,
    const float* __restrict__ b_r3, float* __restrict__ out) {
    int t = blockIdx.x * 256 + threadIdx.x;
    if (t >= 128 * 9) return;
    int r = t / 9, col = t % 9;
    int head = (col == 0) ? 0 : (col == 1) ? 1 : 2;
    int p = (col < 2) ? 0 : col - 2;
    int Pn = (head == 2) ? 7 : 1;
    const float* h2 = h2s + (size_t)head * (128 * 512) + (size_t)r * 512;
    const float* w3 = (head == 0) ? w_c3 : (head == 1) ? w_i3 : w_r3;
    float acc = ((head == 0) ? b_c3 : (head == 1) ? b_i3 : b_r3)[p];
    for (int j = 0; j < 512; j++) acc += h2[j] * w3[j * Pn + p];
    out[r * 9 + col] = acc;
}

extern "C" void kernel_launch(void* const* d_in, const int* in_sizes, int n_in,
                              void* d_out, int out_size, void* d_ws, size_t ws_size,
                              hipStream_t stream) {
    const float* xyz   = (const float*)d_in[0];
    const float* feats = (const float*)d_in[1];
    const float* rois  = (const float*)d_in[2];
    const float* w_m1  = (const float*)d_in[3];
    const float* w_m2  = (const float*)d_in[4];
    const float* w_s1  = (const float*)d_in[5];
    const float* w_s2  = (const float*)d_in[6];
    const float* w_c1  = (const float*)d_in[7];
    const float* w_c2  = (const float*)d_in[8];
    const float* w_c3  = (const float*)d_in[9];
    const float* b_c3  = (const float*)d_in[10];
    const float* w_i1  = (const float*)d_in[11];
    const float* w_i2  = (const float*)d_in[12];
    const float* w_i3  = (const float*)d_in[13];
    const float* b_i3  = (const float*)d_in[14];
    const float* w_r1  = (const float*)d_in[15];
    const float* w_r2  = (const float*)d_in[16];
    const float* w_r3  = (const float*)d_in[17];
    const float* b_r3  = (const float*)d_in[18];
    float* out = (float*)d_out;

    char* ws = (char*)d_ws;
    float*    gp     = (float*)(ws + OFF_GP);
    ushort_t* afh    = (ushort_t*)(ws + OFF_PH);
    ushort_t* afl    = (ushort_t*)(ws + OFF_PL);
    float*    part   = (float*)(ws + OFF_PART);
    int*      cand   = (int*)(ws + OFF_CAND);
    float*    F      = (float*)(ws + OFF_F);
    int*      ncand  = (int*)(ws + OFF_NCAND);
    ushort_t* w1th   = (ushort_t*)(ws + OFF_W1TH);
    ushort_t* w1tl   = (ushort_t*)(ws + OFF_W1TL);
    ushort_t* w2th   = (ushort_t*)(ws + OFF_W2TH);
    ushort_t* w2tl   = (ushort_t*)(ws + OFF_W2TL);
    ushort_t* fhi    = (ushort_t*)(ws + OFF_FHI);
    ushort_t* flo    = (ushort_t*)(ws + OFF_FLO);
    ushort_t* t1h    = (ushort_t*)(ws + OFF_T1H);
    ushort_t* t1l    = (ushort_t*)(ws + OFF_T1L);
    ushort_t* sfch   = (ushort_t*)(ws + OFF_SFCH);
    ushort_t* sfcl   = (ushort_t*)(ws + OFF_SFCL);
    ushort_t* h1h    = (ushort_t*)(ws + OFF_H1H);
    ushort_t* h1l    = (ushort_t*)(ws + OFF_H1L);
    float*    h2s    = (float*)(ws + OFF_H2S);

    // 1. all prep
    hipLaunchKernelGGL(prep_all_k, dim3(2230), dim3(256), 0, stream,
                       rois, xyz, feats, w_m1, w_m2, gp, fhi, flo,
                       w1th, w1tl, w2th, w2tl, cand, ncand);
    // 2. F = feats @ W1f
    hipLaunchKernelGGL(f_gemm_k, dim3(64), dim3(256), 0, stream,
                       fhi, flo, w1th, w1tl, F);
    // 3. pool -> A_frag hi/lo (4 waves/block now)
    hipLaunchKernelGGL(grid_pool_v4_k, dim3(M_GP / 16), dim3(256), 0, stream,
                       xyz, F, gp, cand, ncand, w_m1, w2th, w2tl, afh, afl);
    // 4-5. s1 streaming split-K (512 blocks) + reduce
    hipLaunchKernelGGL(s1v2_k, dim3(32, 2, 8), dim3(256), 0, stream,
                       afh, afl, w_s1, part);
    hipLaunchKernelGGL(reduce_bf_k, dim3(512), dim3(256), 0, stream,
                       part, t1h, t1l, 128 * 1024, 8);
    // 6. s2 fused
    hipLaunchKernelGGL(fused_gemm_k, dim3(8, 1, 1), dim3(256), 0, stream,
                       t1h, t1l, (size_t)0, w_s2, w_s2, w_s2,
                       sfch, sfcl, (float*)nullptr, 0, 512, 1024);
    // 7. heads layer 1 fused
    hipLaunchKernelGGL(fused_gemm_k, dim3(16, 1, 3), dim3(256), 0, stream,
                       sfch, sfcl, (size_t)0, w_c1, w_i1, w_r1,
                       h1h, h1l, (float*)nullptr, 0, 1024, 512);
    // 8. heads layer 2 fused
    hipLaunchKernelGGL(fused_gemm_k, dim3(8, 1, 3), dim3(256), 0, stream,
                       h1h, h1l, (size_t)(128 * 1024), w_c2, w_i2, w_r2,
                       (ushort_t*)nullptr, (ushort_t*)nullptr, h2s, 1, 512, 1024);
    // 9. final projections
    hipLaunchKernelGGL(head_out3_k, dim3(5), dim3(256), 0, stream,
                       h2s, w_c3, w_i3, w_r3, b_c3, b_i3, b_r3, out);
}

// Round 11
// 253.993 us; speedup vs baseline: 1.1307x; 1.1307x over previous
//
#include <hip/hip_runtime.h>

typedef float  f32x4  __attribute__((ext_vector_type(4)));
typedef __bf16 bf16x8 __attribute__((ext_vector_type(8)));
typedef unsigned short ushort_t;

#define N_PTS 4096
#define R_ROIS 128
#define M_GP  27648
#define LDS_FENCE() asm volatile("s_waitcnt lgkmcnt(0)" ::: "memory")

// ---------------- workspace layout (bytes), total 13,763,072 ----------------
static constexpr size_t OFF_GP     = 0;          // 331,776
// A-fragment arrays (pool output, s1 input): [432][128][32] u16 each
static constexpr size_t OFF_PH     = 331776;     // 3,538,944
static constexpr size_t OFF_PL     = 3870720;    // 3,538,944 (end 7,409,664)
// h1s/h2s overlay the A-frag region (dead after s1 GEMM):
static constexpr size_t OFF_H1H    = 331776;     // 3*128*1024*2 = 786,432
static constexpr size_t OFF_H1L    = 1118208;    // 786,432
static constexpr size_t OFF_H2S    = 1904640;    // 786,432 (end 2,691,072)
static constexpr size_t OFF_PART   = 7409664;    // 8*128*1024*4 = 4,194,304 (end 11,603,968)
//   pool-phase overlays inside PART (all dead before s1 writes partials):
static constexpr size_t OFF_CAND   = OFF_PART;   // 128*4096*4 = 2,097,152
static constexpr size_t OFF_F      = 9506816;    // 4096*64*4 = 1,048,576
static constexpr size_t OFF_XYZ4   = 10555392;   // 4096*16 = 65,536 (end 10,620,928)
static constexpr size_t OFF_NCAND  = 11603968;   // 512
static constexpr size_t OFF_W1TH   = 11604480;   // 10752*2
static constexpr size_t OFF_W1TL   = 11625984;   // 10752*2
static constexpr size_t OFF_W2TH   = 11647488;   // 4608*2
static constexpr size_t OFF_W2TL   = 11656704;   // 4608*2 (end 11,665,920)
// fhi/flo live until f_gemm; t1/sfc (FC phase) overlay them:
static constexpr size_t OFF_FHI    = 11665920;   // 1,048,576
static constexpr size_t OFF_FLO    = 12714496;   // 1,048,576 (end 13,763,072)
static constexpr size_t OFF_T1H    = 11665920;   // 262,144
static constexpr size_t OFF_T1L    = 11928064;   // 262,144
static constexpr size_t OFF_SFCH   = 12190208;   // 131,072
static constexpr size_t OFF_SFCL   = 12321280;   // 131,072 (end 12,452,352)

static __device__ inline ushort_t f2bf(float f) {
    unsigned int u = __float_as_uint(f);
    unsigned int r = u + 0x7FFFu + ((u >> 16) & 1u);
    return (ushort_t)(r >> 16);
}
static __device__ inline float bf2f(ushort_t h) {
    return __uint_as_float(((unsigned int)h) << 16);
}

// ---------------- merged prep: gps | weights | feats | xyz4 | roi cand ----
__global__ __launch_bounds__(256) void prep_all_k(
    const float* __restrict__ rois, const float* __restrict__ xyz,
    const float* __restrict__ feats, const float* __restrict__ w1,
    const float* __restrict__ w2, float* __restrict__ gp,
    ushort_t* __restrict__ fhi, ushort_t* __restrict__ flo,
    ushort_t* __restrict__ w1th, ushort_t* __restrict__ w1tl,
    ushort_t* __restrict__ w2th, ushort_t* __restrict__ w2tl,
    float4* __restrict__ xyz4,
    int* __restrict__ cand, int* __restrict__ ncand) {
    int b = blockIdx.x, tid = threadIdx.x;
    if (b < 108) {                       // ---- grid points
        int m = b * 256 + tid;
        int r = m / 216, t = m % 216;
        int gi = t / 36, gj = (t / 6) % 6, gk = t % 6;
        const float* roi = rois + r * 7;
        float sx = roi[3], sy = roi[4], sz = roi[5];
        float lx = ((float)gi + 0.5f) / 6.0f * sx - sx * 0.5f;
        float ly = ((float)gj + 0.5f) / 6.0f * sy - sy * 0.5f;
        float lz = ((float)gk + 0.5f) / 6.0f * sz - sz * 0.5f;
        float c = cosf(roi[6]), s = sinf(roi[6]);
        gp[m * 3 + 0] = lx * c - ly * s + roi[0];
        gp[m * 3 + 1] = lx * s + ly * c + roi[1];
        gp[m * 3 + 2] = lz + roi[2];
    } else if (b < 150) {                // ---- weight prep (permuted transpose + hi/lo)
        int t = (b - 108) * 256 + tid;   // t < 10752
        {
            int col = t / 168, p = t % 168;
            float v = (p < 128) ? w1[(3 + p) * 64 + col]
                    : (p < 131) ? w1[(p - 128) * 64 + col] : 0.f;
            ushort_t hi = f2bf(v);
            w1th[t] = hi;
            w1tl[t] = f2bf(v - bf2f(hi));
        }
        if (t < 4608) {
            int col = t / 72, k = t % 72;
            float v = (k < 64) ? w2[k * 64 + col] : 0.f;
            ushort_t hi = f2bf(v);
            w2th[t] = hi;
            w2tl[t] = f2bf(v - bf2f(hi));
        }
    } else if (b < 2198) {               // ---- feats -> hi/lo bf16
        int i = (b - 150) * 256 + tid;   // i < 524288
        float v = feats[i];
        __bf16 h = (__bf16)v;
        fhi[i] = __builtin_bit_cast(ushort_t, h);
        flo[i] = __builtin_bit_cast(ushort_t, (__bf16)(v - (float)h));
    } else if (b < 2214) {               // ---- xyz -> float4 pack
        int i = (b - 2198) * 256 + tid;  // i < 4096
        xyz4[i] = make_float4(xyz[i * 3 + 0], xyz[i * 3 + 1], xyz[i * 3 + 2], 0.f);
    } else {                             // ---- per-RoI candidate lists (4 waves/block)
        int r = (b - 2214) * 4 + (tid >> 6);
        int lane = tid & 63;
        const float* roi = rois + r * 7;
        float cx = roi[0], cy = roi[1], cz = roi[2];
        float sx = roi[3], sy = roi[4], sz = roi[5];
        float Rc = 0.8f + 0.4166667f * sqrtf(sx * sx + sy * sy + sz * sz) + 0.01f;
        float Rc2 = Rc * Rc;
        int* cl = cand + (size_t)r * N_PTS;
        int cnt = 0;
        for (int base = 0; base < N_PTS; base += 64) {
            int i = base + lane;
            float dx = xyz[i * 3 + 0] - cx;
            float dy = xyz[i * 3 + 1] - cy;
            float dz = xyz[i * 3 + 2] - cz;
            bool in = dx * dx + dy * dy + dz * dz < Rc2;
            unsigned long long ball = __ballot(in);
            int before = __popcll(ball & ((1ull << lane) - 1ull));
            if (in) cl[cnt + before] = i;
            cnt += __popcll(ball);
        }
        if (lane == 0) ncand[r] = cnt;
    }
}

// ---------------- F = feats @ W1f (split-bf16 MFMA), 4096x64 f32 ----------
__global__ __launch_bounds__(256) void f_gemm_k(
    const ushort_t* __restrict__ fhi, const ushort_t* __restrict__ flo,
    const ushort_t* __restrict__ w1th, const ushort_t* __restrict__ w1tl,
    float* __restrict__ F) {
    int tid = threadIdx.x;
    int w = tid >> 6, lane = tid & 63;
    int row = lane & 15, grp = lane >> 4;
    int m0 = blockIdx.x * 64 + w * 16;

    f32x4 acc[4];
#pragma unroll
    for (int nt = 0; nt < 4; nt++) acc[nt] = {0.f, 0.f, 0.f, 0.f};

#pragma unroll
    for (int ks = 0; ks < 4; ks++) {
        size_t ao = (size_t)(m0 + row) * 128 + ks * 32 + grp * 8;
        bf16x8 ah = *(const bf16x8*)&fhi[ao];
        bf16x8 al = *(const bf16x8*)&flo[ao];
#pragma unroll
        for (int nt = 0; nt < 4; nt++) {
            int bo = (nt * 16 + row) * 168 + ks * 32 + grp * 8;
            bf16x8 bh = *(const bf16x8*)&w1th[bo];
            bf16x8 bl = *(const bf16x8*)&w1tl[bo];
            acc[nt] = __builtin_amdgcn_mfma_f32_16x16x32_bf16(ah, bh, acc[nt], 0, 0, 0);
            acc[nt] = __builtin_amdgcn_mfma_f32_16x16x32_bf16(al, bh, acc[nt], 0, 0, 0);
            acc[nt] = __builtin_amdgcn_mfma_f32_16x16x32_bf16(ah, bl, acc[nt], 0, 0, 0);
        }
    }
#pragma unroll
    for (int nt = 0; nt < 4; nt++)
#pragma unroll
        for (int reg = 0; reg < 4; reg++)
            F[(size_t)(m0 + grp * 4 + reg) * 64 + nt * 16 + row] = acc[nt][reg];
}

// ---------------- pool v5: SHARED 4-gp scan + F-gather + stage2 MFMA -------
// 1 wave per block, 4 gps per wave, all 4 in the same RoI (216 % 4 == 0).
// One candidate load per iteration feeds all 4 gps' radius tests.
__global__ __launch_bounds__(64) void grid_pool_v5_k(
    const float4* __restrict__ xyz4, const float* __restrict__ F,
    const float* __restrict__ gp, const int* __restrict__ cand,
    const int* __restrict__ ncand, const float* __restrict__ w_m1,
    const ushort_t* __restrict__ w2th, const ushort_t* __restrict__ w2tl,
    ushort_t* __restrict__ Afh, ushort_t* __restrict__ Afl) {
    __shared__ int s_idx[4][16];
    int lane = threadIdx.x;
    const float R2 = (float)(0.8 * 0.8);
    int row = lane & 15, grp = lane >> 4;
    int m0 = blockIdx.x * 4;
    int r = m0 / 216;                    // shared RoI for all 4 gps

    float gxv[4], gyv[4], gzv[4];
#pragma unroll
    for (int g = 0; g < 4; g++) {
        int m = m0 + g;
        gxv[g] = gp[m * 3 + 0];
        gyv[g] = gp[m * 3 + 1];
        gzv[g] = gp[m * 3 + 2];
    }

    // ---- shared scan: first <=16 in-radius indices per gp (ascending) ----
    int nc = ncand[r];
    const int* cl = cand + (size_t)r * N_PTS;
    int cnt0 = 0, cnt1 = 0, cnt2 = 0, cnt3 = 0;
    for (int base = 0; base < nc; base += 64) {
        int t = base + lane;
        float px = 1e30f, py = 1e30f, pz = 1e30f;
        int i = 0;
        if (t < nc) {
            i = cl[t];
            float4 p = xyz4[i];
            px = p.x; py = p.y; pz = p.z;
        }
#pragma unroll
        for (int g = 0; g < 4; g++) {
            float dx = px - gxv[g], dy = py - gyv[g], dz = pz - gzv[g];
            bool in = dx * dx + dy * dy + dz * dz < R2;
            unsigned long long ball = __ballot(in);
            int before = __popcll(ball & ((1ull << lane) - 1ull));
            int cnt = (g == 0) ? cnt0 : (g == 1) ? cnt1 : (g == 2) ? cnt2 : cnt3;
            int pos = cnt + before;
            if (in && pos < 16) s_idx[g][pos] = i;
            int add = __popcll(ball);
            if (g == 0) cnt0 += add; else if (g == 1) cnt1 += add;
            else if (g == 2) cnt2 += add; else cnt3 += add;
        }
        if (cnt0 >= 16 && cnt1 >= 16 && cnt2 >= 16 && cnt3 >= 16) break;
    }
    LDS_FENCE();

    bool empty[4];
#pragma unroll
    for (int g = 0; g < 4; g++) {
        int cnt = (g == 0) ? cnt0 : (g == 1) ? cnt1 : (g == 2) ? cnt2 : cnt3;
        int c = min(cnt, 16);
        empty[g] = (c == 0);
        if (lane == 0) {
            if (c == 0) {
                for (int p = 0; p < 16; p++) s_idx[g][p] = 0;
            } else {
                int f = s_idx[g][0];
                for (int p = c; p < 16; p++) s_idx[g][p] = f;
            }
        }
    }
    LDS_FENCE();

    int pi[4];
    float rx[4], ry[4], rz[4];
#pragma unroll
    for (int g = 0; g < 4; g++) {
        pi[g] = s_idx[g][row];
        float4 p = xyz4[pi[g]];
        rx[g] = p.x - gxv[g];
        ry[g] = p.y - gyv[g];
        rz[g] = p.z - gzv[g];
    }

    f32x4 p[4][4];
#pragma unroll
    for (int g = 0; g < 4; g++)
#pragma unroll
        for (int nt = 0; nt < 4; nt++) p[g][nt] = {0.f, 0.f, 0.f, 0.f};

#pragma unroll
    for (int ks = 0; ks < 2; ks++) {
        // W1r slice for this lane's 8 channels (rows 0..2 of w_m1, exact fp32)
        float w1r0[8], w1r1[8], w1r2[8];
        {
            const float* wp = w_m1 + ks * 32 + grp * 8;
            *(float4*)&w1r0[0] = *(const float4*)(wp);
            *(float4*)&w1r0[4] = *(const float4*)(wp + 4);
            *(float4*)&w1r1[0] = *(const float4*)(wp + 64);
            *(float4*)&w1r1[4] = *(const float4*)(wp + 68);
            *(float4*)&w1r2[0] = *(const float4*)(wp + 128);
            *(float4*)&w1r2[4] = *(const float4*)(wp + 132);
        }
        bf16x8 zah[4], zal[4];
#pragma unroll
        for (int g = 0; g < 4; g++) {
            const float* Fr = F + (size_t)pi[g] * 64 + ks * 32 + grp * 8;
            float fv[8];
            *(float4*)&fv[0] = *(const float4*)Fr;
            *(float4*)&fv[4] = *(const float4*)(Fr + 4);
            bf16x8 hh, ll;
#pragma unroll
            for (int j = 0; j < 8; j++) {
                float zv = fv[j] + rx[g] * w1r0[j] + ry[g] * w1r1[j] + rz[g] * w1r2[j];
                float v = fmaxf(zv, 0.f);
                __bf16 h = (__bf16)v;
                hh[j] = h;
                ll[j] = (__bf16)(v - (float)h);
            }
            zah[g] = hh; zal[g] = ll;
        }
#pragma unroll
        for (int nt = 0; nt < 4; nt++) {
            int bo = (nt * 16 + row) * 72 + ks * 32 + grp * 8;
            bf16x8 bh = *(const bf16x8*)&w2th[bo];
            bf16x8 bl = *(const bf16x8*)&w2tl[bo];
#pragma unroll
            for (int g = 0; g < 4; g++) {
                p[g][nt] = __builtin_amdgcn_mfma_f32_16x16x32_bf16(zah[g], bh, p[g][nt], 0, 0, 0);
                p[g][nt] = __builtin_amdgcn_mfma_f32_16x16x32_bf16(zal[g], bh, p[g][nt], 0, 0, 0);
                p[g][nt] = __builtin_amdgcn_mfma_f32_16x16x32_bf16(zah[g], bl, p[g][nt], 0, 0, 0);
            }
        }
    }

#pragma unroll
    for (int g = 0; g < 4; g++) {
        int m = m0 + g;
        int t = m % 216;
#pragma unroll
        for (int nt = 0; nt < 4; nt++) {
            float mv = fmaxf(fmaxf(fmaxf(p[g][nt][0], p[g][nt][1]),
                                   fmaxf(p[g][nt][2], p[g][nt][3])), 0.f);
            mv = fmaxf(mv, __shfl_xor(mv, 16));
            mv = fmaxf(mv, __shfl_xor(mv, 32));
            if (grp == 0) {
                float v = empty[g] ? 0.f : mv;
                __bf16 h = (__bf16)v;
                int kt = t * 2 + (nt >> 1);
                size_t o = ((size_t)kt * 128 + r) * 32 + (nt & 1) * 16 + row;
                Afh[o] = __builtin_bit_cast(ushort_t, h);
                Afl[o] = __builtin_bit_cast(ushort_t, (__bf16)(v - (float)h));
            }
        }
    }
}

// ---------------- s1 v2: streaming split-bf16 MFMA, A-frags direct ---------
// BM=64, BN=32, S=8. grid (32, 2, 8) = 512 blocks, 256 threads.
__global__ __launch_bounds__(256) void s1v2_k(
    const ushort_t* __restrict__ Afh, const ushort_t* __restrict__ Afl,
    const float* __restrict__ B, float* __restrict__ P) {
    __shared__ __attribute__((aligned(16))) ushort_t Bs_h[32][40];
    __shared__ __attribute__((aligned(16))) ushort_t Bs_l[32][40];
    const int N = 1024, STEPS = 54;
    int tid = threadIdx.x;
    int w = tid >> 6, lane = tid & 63;
    int row = lane & 15, grp = lane >> 4;
    int n0 = blockIdx.x * 32, m0 = blockIdx.y * 64;
    int s = blockIdx.z;
    int kt0 = s * STEPS;
    int krow = tid >> 3, nn = (tid & 7) * 4;

    f32x4 acc[2];
    acc[0] = {0.f, 0.f, 0.f, 0.f};
    acc[1] = {0.f, 0.f, 0.f, 0.f};

    int arow = m0 + w * 16 + row;
    size_t aoff = ((size_t)kt0 * 128 + arow) * 32 + grp * 8;
    const float* bp = B + (size_t)(kt0 * 32 + krow) * N + n0 + nn;

    float4 vb = *(const float4*)bp;
    bf16x8 ah = *(const bf16x8*)&Afh[aoff];
    bf16x8 al = *(const bf16x8*)&Afl[aoff];

    for (int kts = 0; kts < STEPS; ++kts) {
        {   // stage current B tile into LDS (transpose + hi/lo convert)
            float vv[4] = {vb.x, vb.y, vb.z, vb.w};
#pragma unroll
            for (int j = 0; j < 4; j++) {
                __bf16 h = (__bf16)vv[j];
                Bs_h[nn + j][krow] = __builtin_bit_cast(ushort_t, h);
                Bs_l[nn + j][krow] = __builtin_bit_cast(ushort_t, (__bf16)(vv[j] - (float)h));
            }
        }
        __syncthreads();
        float4 vb_n;
        bf16x8 ah_n, al_n;
        if (kts + 1 < STEPS) {            // issue next-tile loads early
            bp += 32 * N;
            vb_n = *(const float4*)bp;
            size_t an = aoff + (size_t)(kts + 1) * 4096;
            ah_n = *(const bf16x8*)&Afh[an];
            al_n = *(const bf16x8*)&Afl[an];
        }
#pragma unroll
        for (int ni = 0; ni < 2; ni++) {
            bf16x8 bh = *(const bf16x8*)&Bs_h[ni * 16 + row][grp * 8];
            bf16x8 bl = *(const bf16x8*)&Bs_l[ni * 16 + row][grp * 8];
            acc[ni] = __builtin_amdgcn_mfma_f32_16x16x32_bf16(ah, bh, acc[ni], 0, 0, 0);
            acc[ni] = __builtin_amdgcn_mfma_f32_16x16x32_bf16(al, bh, acc[ni], 0, 0, 0);
            acc[ni] = __builtin_amdgcn_mfma_f32_16x16x32_bf16(ah, bl, acc[ni], 0, 0, 0);
        }
        __syncthreads();
        if (kts + 1 < STEPS) { vb = vb_n; ah = ah_n; al = al_n; }
    }
    size_t pb = (size_t)s * 128 * N;
#pragma unroll
    for (int ni = 0; ni < 2; ni++)
#pragma unroll
        for (int reg = 0; reg < 4; reg++) {
            int mrow = m0 + w * 16 + grp * 4 + reg;
            P[pb + (size_t)mrow * N + n0 + ni * 16 + row] = acc[ni][reg];
        }
}

// ======== split-bf16 MFMA GEMM: A pre-split u16 hi/lo, B f32 ========
// BM=128, BN=64, BK=32, 256 threads. (used by s2 / heads — K <= 1024)
__device__ inline void gemm_body(const ushort_t* __restrict__ Ah,
                                 const ushort_t* __restrict__ Al,
                                 const float* __restrict__ B,
                                 f32x4 (&acc)[2][4],
                                 int N, int Kt, int k0, int klen, int n0) {
    __shared__ __attribute__((aligned(16))) ushort_t As_h[128][40];
    __shared__ __attribute__((aligned(16))) ushort_t As_l[128][40];
    __shared__ __attribute__((aligned(16))) ushort_t Bs_h[64][40];
    __shared__ __attribute__((aligned(16))) ushort_t Bs_l[64][40];
    int tid = threadIdx.x;
    int w = tid >> 6, lane = tid & 63;
    int row = lane & 15, grp = lane >> 4;

    for (int kt = 0; kt < klen; kt += 32) {
        {   // A copy: 128 rows x 32 u16 per array; 2 threads/row, 2 uint4 each
            int arow = tid >> 1, koff = (tid & 1) * 16;
            size_t so = (size_t)arow * Kt + k0 + kt + koff;
            *(uint4*)&As_h[arow][koff]     = *(const uint4*)(Ah + so);
            *(uint4*)&As_h[arow][koff + 8] = *(const uint4*)(Ah + so + 8);
            *(uint4*)&As_l[arow][koff]     = *(const uint4*)(Al + so);
            *(uint4*)&As_l[arow][koff + 8] = *(const uint4*)(Al + so + 8);
        }
        {   // B stage + convert, transposed: Bs[n][k]
            int kr = tid >> 4;
            int nn = (tid & 15) * 4;
#pragma unroll
            for (int i = 0; i < 2; i++) {
                int krow = kr + i * 16;
                float4 v = *(const float4*)(B + (size_t)(k0 + kt + krow) * N + n0 + nn);
                float vv[4] = {v.x, v.y, v.z, v.w};
#pragma unroll
                for (int j = 0; j < 4; j++) {
                    __bf16 h = (__bf16)vv[j];
                    Bs_h[nn + j][krow] = __builtin_bit_cast(ushort_t, h);
                    Bs_l[nn + j][krow] = __builtin_bit_cast(ushort_t, (__bf16)(vv[j] - (float)h));
                }
            }
        }
        __syncthreads();
#pragma unroll
        for (int mi = 0; mi < 2; mi++) {
            int arow = (w * 2 + mi) * 16 + row;
            bf16x8 ah = *(const bf16x8*)&As_h[arow][grp * 8];
            bf16x8 al = *(const bf16x8*)&As_l[arow][grp * 8];
#pragma unroll
            for (int ni = 0; ni < 4; ni++) {
                bf16x8 bh = *(const bf16x8*)&Bs_h[ni * 16 + row][grp * 8];
                bf16x8 bl = *(const bf16x8*)&Bs_l[ni * 16 + row][grp * 8];
                acc[mi][ni] = __builtin_amdgcn_mfma_f32_16x16x32_bf16(ah, bh, acc[mi][ni], 0, 0, 0);
                acc[mi][ni] = __builtin_amdgcn_mfma_f32_16x16x32_bf16(al, bh, acc[mi][ni], 0, 0, 0);
                acc[mi][ni] = __builtin_amdgcn_mfma_f32_16x16x32_bf16(ah, bl, acc[mi][ni], 0, 0, 0);
            }
        }
        __syncthreads();
    }
}

// fused full-K GEMM + relu; out bf16 hi/lo or f32. grid (N/64, 1, heads)
__global__ __launch_bounds__(256) void fused_gemm_k(
    const ushort_t* __restrict__ A_h, const ushort_t* __restrict__ A_l,
    size_t a_stride,
    const float* __restrict__ B0, const float* __restrict__ B1,
    const float* __restrict__ B2,
    ushort_t* __restrict__ C_h, ushort_t* __restrict__ C_l,
    float* __restrict__ C_f, int out_f32, int N, int Kt) {
    int tid = threadIdx.x;
    int w = tid >> 6, lane = tid & 63;
    int row = lane & 15, grp = lane >> 4;
    int head = blockIdx.z, n0 = blockIdx.x * 64;
    const float* B = (head == 0) ? B0 : (head == 1) ? B1 : B2;
    const ushort_t* Ah = A_h + (size_t)head * a_stride;
    const ushort_t* Al = A_l + (size_t)head * a_stride;
    f32x4 acc[2][4];
#pragma unroll
    for (int mi = 0; mi < 2; mi++)
#pragma unroll
        for (int ni = 0; ni < 4; ni++) acc[mi][ni] = {0.f, 0.f, 0.f, 0.f};
    gemm_body(Ah, Al, B, acc, N, Kt, 0, Kt, n0);
    size_t ob = (size_t)head * 128 * N;
#pragma unroll
    for (int mi = 0; mi < 2; mi++)
#pragma unroll
        for (int ni = 0; ni < 4; ni++)
#pragma unroll
            for (int reg = 0; reg < 4; reg++) {
                int mrow = (w * 2 + mi) * 16 + grp * 4 + reg;
                size_t o = ob + (size_t)mrow * N + n0 + ni * 16 + row;
                float v = fmaxf(acc[mi][ni][reg], 0.f);
                if (out_f32) {
                    C_f[o] = v;
                } else {
                    __bf16 h = (__bf16)v;
                    C_h[o] = __builtin_bit_cast(ushort_t, h);
                    C_l[o] = __builtin_bit_cast(ushort_t, (__bf16)(v - (float)h));
                }
            }
}

// reduce partials + relu -> hi/lo bf16
__global__ __launch_bounds__(256) void reduce_bf_k(const float* __restrict__ P,
                                                   ushort_t* __restrict__ C_h,
                                                   ushort_t* __restrict__ C_l,
                                                   int MN, int S) {
    int i = blockIdx.x * 256 + threadIdx.x;
    if (i >= MN) return;
    float v = 0.f;
    for (int s = 0; s < S; s++) v += P[(size_t)s * MN + i];
    v = fmaxf(v, 0.f);
    __bf16 h = (__bf16)v;
    C_h[i] = __builtin_bit_cast(ushort_t, h);
    C_l[i] = __builtin_bit_cast(ushort_t, (__bf16)(v - (float)h));
}

// ---------------- final head projections (merged) ----------------
__global__ __launch_bounds__(256) void head_out3_k(
    const float* __restrict__ h2s, const float* __restrict__ w_c3,
    const float* __restrict__ w_i3, const float* __restrict__ w_r3,
    const float* __restrict__ b_c3, const float* __restrict__ b_i3,
    const float* __restrict__ b_r3, float* __restrict__ out) {
    int t = blockIdx.x * 256 + threadIdx.x;
    if (t >= 128 * 9) return;
    int r = t / 9, col = t % 9;
    int head = (col == 0) ? 0 : (col == 1) ? 1 : 2;
    int p = (col < 2) ? 0 : col - 2;
    int Pn = (head == 2) ? 7 : 1;
    const float* h2 = h2s + (size_t)head * (128 * 512) + (size_t)r * 512;
    const float* w3 = (head == 0) ? w_c3 : (head == 1) ? w_i3 : w_r3;
    float acc = ((head == 0) ? b_c3 : (head == 1) ? b_i3 : b_r3)[p];
    for (int j = 0; j < 512; j++) acc += h2[j] * w3[j * Pn + p];
    out[r * 9 + col] = acc;
}

extern "C" void kernel_launch(void* const* d_in, const int* in_sizes, int n_in,
                              void* d_out, int out_size, void* d_ws, size_t ws_size,
                              hipStream_t stream) {
    const float* xyz   = (const float*)d_in[0];
    const float* feats = (const float*)d_in[1];
    const float* rois  = (const float*)d_in[2];
    const float* w_m1  = (const float*)d_in[3];
    const float* w_m2  = (const float*)d_in[4];
    const float* w_s1  = (const float*)d_in[5];
    const float* w_s2  = (const float*)d_in[6];
    const float* w_c1  = (const float*)d_in[7];
    const float* w_c2  = (const float*)d_in[8];
    const float* w_c3  = (const float*)d_in[9];
    const float* b_c3  = (const float*)d_in[10];
    const float* w_i1  = (const float*)d_in[11];
    const float* w_i2  = (const float*)d_in[12];
    const float* w_i3  = (const float*)d_in[13];
    const float* b_i3  = (const float*)d_in[14];
    const float* w_r1  = (const float*)d_in[15];
    const float* w_r2  = (const float*)d_in[16];
    const float* w_r3  = (const float*)d_in[17];
    const float* b_r3  = (const float*)d_in[18];
    float* out = (float*)d_out;

    char* ws = (char*)d_ws;
    float*    gp     = (float*)(ws + OFF_GP);
    ushort_t* afh    = (ushort_t*)(ws + OFF_PH);
    ushort_t* afl    = (ushort_t*)(ws + OFF_PL);
    float*    part   = (float*)(ws + OFF_PART);
    int*      cand   = (int*)(ws + OFF_CAND);
    float*    F      = (float*)(ws + OFF_F);
    float4*   xyz4   = (float4*)(ws + OFF_XYZ4);
    int*      ncand  = (int*)(ws + OFF_NCAND);
    ushort_t* w1th   = (ushort_t*)(ws + OFF_W1TH);
    ushort_t* w1tl   = (ushort_t*)(ws + OFF_W1TL);
    ushort_t* w2th   = (ushort_t*)(ws + OFF_W2TH);
    ushort_t* w2tl   = (ushort_t*)(ws + OFF_W2TL);
    ushort_t* fhi    = (ushort_t*)(ws + OFF_FHI);
    ushort_t* flo    = (ushort_t*)(ws + OFF_FLO);
    ushort_t* t1h    = (ushort_t*)(ws + OFF_T1H);
    ushort_t* t1l    = (ushort_t*)(ws + OFF_T1L);
    ushort_t* sfch   = (ushort_t*)(ws + OFF_SFCH);
    ushort_t* sfcl   = (ushort_t*)(ws + OFF_SFCL);
    ushort_t* h1h    = (ushort_t*)(ws + OFF_H1H);
    ushort_t* h1l    = (ushort_t*)(ws + OFF_H1L);
    float*    h2s    = (float*)(ws + OFF_H2S);

    // 1. all prep (gps | weights | feats hi/lo | xyz4 | roi cand)
    hipLaunchKernelGGL(prep_all_k, dim3(2246), dim3(256), 0, stream,
                       rois, xyz, feats, w_m1, w_m2, gp, fhi, flo,
                       w1th, w1tl, w2th, w2tl, xyz4, cand, ncand);
    // 2. F = feats @ W1f
    hipLaunchKernelGGL(f_gemm_k, dim3(64), dim3(256), 0, stream,
                       fhi, flo, w1th, w1tl, F);
    // 3. pool -> A_frag hi/lo (shared 4-gp scan)
    hipLaunchKernelGGL(grid_pool_v5_k, dim3(M_GP / 4), dim3(64), 0, stream,
                       xyz4, F, gp, cand, ncand, w_m1, w2th, w2tl, afh, afl);
    // 4-5. s1 streaming split-K (512 blocks) + reduce
    hipLaunchKernelGGL(s1v2_k, dim3(32, 2, 8), dim3(256), 0, stream,
                       afh, afl, w_s1, part);
    hipLaunchKernelGGL(reduce_bf_k, dim3(512), dim3(256), 0, stream,
                       part, t1h, t1l, 128 * 1024, 8);
    // 6. s2 fused
    hipLaunchKernelGGL(fused_gemm_k, dim3(8, 1, 1), dim3(256), 0, stream,
                       t1h, t1l, (size_t)0, w_s2, w_s2, w_s2,
                       sfch, sfcl, (float*)nullptr, 0, 512, 1024);
    // 7. heads layer 1 fused
    hipLaunchKernelGGL(fused_gemm_k, dim3(16, 1, 3), dim3(256), 0, stream,
                       sfch, sfcl, (size_t)0, w_c1, w_i1, w_r1,
                       h1h, h1l, (float*)nullptr, 0, 1024, 512);
    // 8. heads layer 2 fused
    hipLaunchKernelGGL(fused_gemm_k, dim3(8, 1, 3), dim3(256), 0, stream,
                       h1h, h1l, (size_t)(128 * 1024), w_c2, w_i2, w_r2,
                       (ushort_t*)nullptr, (ushort_t*)nullptr, h2s, 1, 512, 1024);
    // 9. final projections
    hipLaunchKernelGGL(head_out3_k, dim3(5), dim3(256), 0, stream,
                       h2s, w_c3, w_i3, w_r3, b_c3, b_i3, b_r3, out);
}